// Round 1
// baseline (2102.665 us; speedup 1.0000x reference)
//
#include <hip/hip_runtime.h>
#include <cstdint>
#include <cstddef>

// Problem constants
#define BN_   16
#define LN_   1024
#define DM_   384
#define DI_   768
#define NS_   16
#define RDT_  24
#define NDBC_ 56

static __device__ __forceinline__ float silu_f(float x) {
    return x / (1.0f + __expf(-x));
}
static __device__ __forceinline__ float softplus_f(float x) {
    return (x > 20.0f) ? x : log1pf(__expf(x));
}

// ---------------------------------------------------------------------------
// LayerNorm: one wave (64 lanes) per row of 384; block = 4 rows.
// x indexed globally (row0 offset), xn written group-local.
// ---------------------------------------------------------------------------
__global__ __launch_bounds__(256) void ln_kernel(
    const float* __restrict__ x, const float* __restrict__ w,
    const float* __restrict__ b, float* __restrict__ xn,
    int row0, int nrows)
{
    int r = blockIdx.x * 4 + (threadIdx.x >> 6);
    if (r >= nrows) return;
    int lane = threadIdx.x & 63;
    const float* xr = x + (size_t)(row0 + r) * DM_;
    float v[6];
    float s = 0.0f;
#pragma unroll
    for (int i = 0; i < 6; i++) { v[i] = xr[lane + 64 * i]; s += v[i]; }
#pragma unroll
    for (int o = 32; o > 0; o >>= 1) s += __shfl_down(s, o, 64);
    s = __shfl(s, 0, 64);
    float mu = s * (1.0f / DM_);
    float q = 0.0f;
#pragma unroll
    for (int i = 0; i < 6; i++) { float d = v[i] - mu; q += d * d; }
#pragma unroll
    for (int o = 32; o > 0; o >>= 1) q += __shfl_down(q, o, 64);
    q = __shfl(q, 0, 64);
    float rstd = rsqrtf(q * (1.0f / DM_) + 1e-5f);
    float* outp = xn + (size_t)r * DM_;
#pragma unroll
    for (int i = 0; i < 6; i++) {
        int c = lane + 64 * i;
        outp[c] = (v[i] - mu) * rstd * w[c] + b[c];
    }
}

// ---------------------------------------------------------------------------
// Generic fp32 GEMM: C[M x N] = (A (+A2)) [M x K] * W[N x K]^T (+ R)
// BM=128, BN=64, BK=16, TM=8, TN=4, 256 threads.
// M must be a multiple of 128, K a multiple of 16, N a multiple of 4.
// R and C are passed pre-offset by the host when they are global buffers.
// ---------------------------------------------------------------------------
__global__ __launch_bounds__(256) void gemm_kernel(
    const float* __restrict__ A, const float* __restrict__ A2,
    const float* __restrict__ W, const float* __restrict__ R,
    float* __restrict__ C, int M, int N, int K)
{
    __shared__ float As[16][128 + 4];
    __shared__ float Ws[16][64 + 4];
    int tid = threadIdx.x;
    int bm = blockIdx.x * 128;
    int bn = blockIdx.y * 64;
    int tx = tid & 15;       // N dim: 16 x 4
    int ty = tid >> 4;       // M dim: 16 x 8
    float acc[8][4] = {};

    int ar = tid >> 2;        // 0..63
    int ak = (tid & 3) * 4;   // 0,4,8,12

    for (int k0 = 0; k0 < K; k0 += 16) {
        // Stage A tile (128 x 16), transposed into As[k][m]
#pragma unroll
        for (int h = 0; h < 2; h++) {
            int row = bm + ar + 64 * h;
            float4 v = *(const float4*)(A + (size_t)row * K + k0 + ak);
            if (A2) {
                float4 a2 = *(const float4*)(A2 + (size_t)row * K + k0 + ak);
                v.x += a2.x; v.y += a2.y; v.z += a2.z; v.w += a2.w;
            }
            As[ak + 0][ar + 64 * h] = v.x;
            As[ak + 1][ar + 64 * h] = v.y;
            As[ak + 2][ar + 64 * h] = v.z;
            As[ak + 3][ar + 64 * h] = v.w;
        }
        // Stage W tile (64 x 16), transposed into Ws[k][n]
        {
            int wrow = bn + ar;
            float4 v = make_float4(0.f, 0.f, 0.f, 0.f);
            if (wrow < N) v = *(const float4*)(W + (size_t)wrow * K + k0 + ak);
            Ws[ak + 0][ar] = v.x;
            Ws[ak + 1][ar] = v.y;
            Ws[ak + 2][ar] = v.z;
            Ws[ak + 3][ar] = v.w;
        }
        __syncthreads();
#pragma unroll
        for (int kk = 0; kk < 16; kk++) {
            float4 a0 = *(float4*)&As[kk][ty * 8];
            float4 a1 = *(float4*)&As[kk][ty * 8 + 4];
            float4 b0 = *(float4*)&Ws[kk][tx * 4];
            float a[8] = {a0.x, a0.y, a0.z, a0.w, a1.x, a1.y, a1.z, a1.w};
            float w4[4] = {b0.x, b0.y, b0.z, b0.w};
#pragma unroll
            for (int i = 0; i < 8; i++)
#pragma unroll
                for (int j = 0; j < 4; j++)
                    acc[i][j] = fmaf(a[i], w4[j], acc[i][j]);
        }
        __syncthreads();
    }

    int col = bn + tx * 4;
    if (col < N) {
#pragma unroll
        for (int i = 0; i < 8; i++) {
            int row = bm + ty * 8 + i;
            float4 o = make_float4(acc[i][0], acc[i][1], acc[i][2], acc[i][3]);
            if (R) {
                float4 r4 = *(const float4*)(R + (size_t)row * N + col);
                o.x += r4.x; o.y += r4.y; o.z += r4.z; o.w += r4.w;
            }
            *(float4*)(C + (size_t)row * N + col) = o;
        }
    }
}

// ---------------------------------------------------------------------------
// Causal depthwise conv (K=4) + silu, both directions in one launch.
// xz group-local (gB batches). dir=1 operates on the L-flipped sequence.
// ---------------------------------------------------------------------------
__global__ __launch_bounds__(256) void conv_kernel(
    const float* __restrict__ xz,
    const float* __restrict__ wf, const float* __restrict__ bf,
    const float* __restrict__ wb, const float* __restrict__ bb,
    float* __restrict__ xhf, float* __restrict__ xhb, int gB)
{
    int idx = blockIdx.x * 256 + threadIdx.x;
    int total = gB * LN_ * DI_;
    int dir = 0;
    if (idx >= total) { idx -= total; dir = 1; }
    int d = idx % DI_;
    int l = (idx / DI_) & (LN_ - 1);
    int b = idx / (DI_ * LN_);
    const float* w = dir ? wb : wf;
    float s = (dir ? bb : bf)[d];
#pragma unroll
    for (int k = 0; k < 4; k++) {
        int j = l - 3 + k;
        if (j < 0) continue;
        int ls = dir ? (LN_ - 1 - j) : j;
        s += w[d * 4 + k] * xz[((size_t)(b * LN_ + ls)) * (2 * DI_) + d];
    }
    float* xh = dir ? xhb : xhf;
    xh[((size_t)(b * LN_ + l)) * DI_ + d] = silu_f(s);
}

// ---------------------------------------------------------------------------
// delta = softplus(dt @ dt_w^T + dt_b). One block per (dir, row).
// ---------------------------------------------------------------------------
__global__ __launch_bounds__(256) void delta_kernel(
    const float* __restrict__ dbcf, const float* __restrict__ dbcb,
    const float* __restrict__ wtf, const float* __restrict__ btf,
    const float* __restrict__ wtb, const float* __restrict__ btb,
    float* __restrict__ deltaf, float* __restrict__ deltab, int rows)
{
    int m = blockIdx.x;
    int dir = 0;
    if (m >= rows) { m -= rows; dir = 1; }
    const float* dbc = (dir ? dbcb : dbcf) + (size_t)m * NDBC_;
    __shared__ float sdt[RDT_];
    if (threadIdx.x < RDT_) sdt[threadIdx.x] = dbc[threadIdx.x];
    __syncthreads();
    const float* wt = dir ? wtb : wtf;
    const float* bt = dir ? btb : btf;
    float* outp = (dir ? deltab : deltaf) + (size_t)m * DI_;
    for (int d = threadIdx.x; d < DI_; d += 256) {
        float s = bt[d];
#pragma unroll
        for (int r = 0; r < RDT_; r++) s = fmaf(sdt[r], wt[d * RDT_ + r], s);
        outp[d] = softplus_f(s);
    }
}

// ---------------------------------------------------------------------------
// Selective scan, both directions in one launch.
// grid = 2 * gB * 3 blocks (dir, batch, d-chunk of 256). 256 threads,
// one thread per channel d; h[16] and A[16] in registers; B/C staged in
// LDS 128 steps at a time. Gated output written at unflipped position.
// ---------------------------------------------------------------------------
__global__ __launch_bounds__(256) void scan_kernel(
    const float* __restrict__ xhf, const float* __restrict__ deltaf,
    const float* __restrict__ dbcf,
    const float* __restrict__ xhb, const float* __restrict__ deltab,
    const float* __restrict__ dbcb,
    const float* __restrict__ alogf, const float* __restrict__ dvf,
    const float* __restrict__ alogb, const float* __restrict__ dvb,
    const float* __restrict__ xz,
    float* __restrict__ yf, float* __restrict__ yb, int gB)
{
    int bid = blockIdx.x;
    int dir = bid / (gB * 3);
    bid -= dir * gB * 3;
    int b = bid / 3;
    int chunk = bid - b * 3;
    int d = chunk * 256 + threadIdx.x;

    const float* xh    = dir ? xhb    : xhf;
    const float* delta = dir ? deltab : deltaf;
    const float* dbc   = dir ? dbcb   : dbcf;
    const float* alog  = dir ? alogb  : alogf;
    const float* dv    = dir ? dvb    : dvf;
    float* y           = dir ? yb     : yf;

    float An[NS_];
#pragma unroll
    for (int n = 0; n < NS_; n++) An[n] = -__expf(alog[d * NS_ + n]);
    float Dd = dv[d];
    float h[NS_];
#pragma unroll
    for (int n = 0; n < NS_; n++) h[n] = 0.0f;

    __shared__ float sBC[128 * 32];
    size_t rb = (size_t)b * LN_;

    for (int c0 = 0; c0 < LN_; c0 += 128) {
        __syncthreads();
        // stage B|C (cols 24..55 of dbc) for 128 steps: 1024 float4 loads
#pragma unroll
        for (int i = 0; i < 4; i++) {
            int t = threadIdx.x + 256 * i;
            int lr = t >> 3;
            int c4 = (t & 7) * 4;
            float4 v = *(const float4*)(dbc + (rb + c0 + lr) * NDBC_ + RDT_ + c4);
            *(float4*)&sBC[lr * 32 + c4] = v;
        }
        __syncthreads();

        for (int lr = 0; lr < 128; lr++) {
            int l = c0 + lr;
            size_t base = (rb + l) * DI_ + d;
            float dt = delta[base];
            float u  = xh[base];
            float du = dt * u;
            const float* bc = &sBC[lr * 32];
            float yv = 0.0f;
#pragma unroll
            for (int n = 0; n < NS_; n++) {
                float dA = __expf(dt * An[n]);
                h[n] = fmaf(h[n], dA, du * bc[n]);
                yv = fmaf(h[n], bc[16 + n], yv);
            }
            yv = fmaf(u, Dd, yv);
            int lo = dir ? (LN_ - 1 - l) : l;
            float z = xz[(rb + lo) * (2 * DI_) + DI_ + d];
            y[(rb + lo) * DI_ + d] = yv * silu_f(z);
        }
    }
}

// ---------------------------------------------------------------------------
// Host launcher. Batch dim is split into groups so workspace fits ws_size.
// ---------------------------------------------------------------------------
extern "C" void kernel_launch(void* const* d_in, const int* in_sizes, int n_in,
                              void* d_out, int out_size, void* d_ws, size_t ws_size,
                              hipStream_t stream)
{
    const float* x         = (const float*)d_in[0];
    const float* ln_w      = (const float*)d_in[1];
    const float* ln_b      = (const float*)d_in[2];
    const float* in_proj_w = (const float*)d_in[3];
    const float* out_proj_w= (const float*)d_in[4];
    const float* conv_wf   = (const float*)d_in[5];
    const float* conv_bf   = (const float*)d_in[6];
    const float* xproj_f   = (const float*)d_in[7];
    const float* dt_wf     = (const float*)d_in[8];
    const float* dt_bf     = (const float*)d_in[9];
    const float* alog_f    = (const float*)d_in[10];
    const float* dv_f      = (const float*)d_in[11];
    const float* conv_wb   = (const float*)d_in[12];
    const float* conv_bb   = (const float*)d_in[13];
    const float* xproj_b   = (const float*)d_in[14];
    const float* dt_wb     = (const float*)d_in[15];
    const float* dt_bb     = (const float*)d_in[16];
    const float* alog_b    = (const float*)d_in[17];
    const float* dv_b      = (const float*)d_in[18];
    float* outp = (float*)d_out;

    // per-batch workspace: rows=1024 -> 6640 floats/row + padding slack
    size_t per_b_bytes = (size_t)LN_ * 6640 * 4;
    int g = BN_;
    while (g > 1 && (size_t)g * per_b_bytes + (size_t)(1 << 16) > ws_size) g >>= 1;

    for (int b0 = 0; b0 < BN_; b0 += g) {
        int rows = g * LN_;
        float* p = (float*)d_ws;
        auto alloc = [&](size_t nfloats) {
            float* r = p;
            p += ((nfloats + 63) & ~(size_t)63);
            return r;
        };
        float* XN   = alloc((size_t)rows * DM_);
        float* XZ   = alloc((size_t)rows * 2 * DI_);
        float* XHf  = alloc((size_t)rows * DI_);
        float* XHb  = alloc((size_t)rows * DI_);
        float* DBCf = alloc((size_t)rows * NDBC_);
        float* DBCb = alloc((size_t)rows * NDBC_);
        float* DLf  = alloc((size_t)rows * DI_);
        float* DLb  = alloc((size_t)rows * DI_);
        float* Yf   = alloc((size_t)rows * DI_);
        float* Yb   = alloc((size_t)rows * DI_);
        int row0 = b0 * LN_;

        ln_kernel<<<rows / 4, 256, 0, stream>>>(x, ln_w, ln_b, XN, row0, rows);

        gemm_kernel<<<dim3(rows / 128, (2 * DI_) / 64), 256, 0, stream>>>(
            XN, nullptr, in_proj_w, nullptr, XZ, rows, 2 * DI_, DM_);

        conv_kernel<<<(2 * rows * DI_) / 256, 256, 0, stream>>>(
            XZ, conv_wf, conv_bf, conv_wb, conv_bb, XHf, XHb, g);

        gemm_kernel<<<dim3(rows / 128, 1), 256, 0, stream>>>(
            XHf, nullptr, xproj_f, nullptr, DBCf, rows, NDBC_, DI_);
        gemm_kernel<<<dim3(rows / 128, 1), 256, 0, stream>>>(
            XHb, nullptr, xproj_b, nullptr, DBCb, rows, NDBC_, DI_);

        delta_kernel<<<2 * rows, 256, 0, stream>>>(
            DBCf, DBCb, dt_wf, dt_bf, dt_wb, dt_bb, DLf, DLb, rows);

        scan_kernel<<<2 * g * 3, 256, 0, stream>>>(
            XHf, DLf, DBCf, XHb, DLb, DBCb,
            alog_f, dv_f, alog_b, dv_b, XZ, Yf, Yb, g);

        gemm_kernel<<<dim3(rows / 128, DM_ / 64), 256, 0, stream>>>(
            Yf, Yb, out_proj_w, x + (size_t)row0 * DM_,
            outp + (size_t)row0 * DM_, rows, DM_, DI_);
    }
}

// Round 2
// 927.178 us; speedup vs baseline: 2.2678x; 2.2678x over previous
//
#include <hip/hip_runtime.h>
#include <cstdint>
#include <cstddef>

// Problem constants
#define BN_   16
#define LN_   1024
#define DM_   384
#define DI_   768
#define NS_   16
#define RDT_  24
#define NDBC_ 56
#define NC_   16
#define LC_   64

typedef unsigned short ushortT;
typedef short bf16x8 __attribute__((ext_vector_type(8)));
typedef float f32x4 __attribute__((ext_vector_type(4)));

static __device__ __forceinline__ float silu_f(float x) {
    return x / (1.0f + __expf(-x));
}
static __device__ __forceinline__ float softplus_f(float x) {
    return (x > 20.0f) ? x : log1pf(__expf(x));
}
static __device__ __forceinline__ ushortT f2bf(float f) {
    union { float f; uint32_t u; } v; v.f = f;
    uint32_t u = v.u;
    uint32_t r = u + 0x7fffu + ((u >> 16) & 1u);
    return (ushortT)(r >> 16);
}

// ---------------------------------------------------------------------------
// Convert the two big weight matrices fp32 -> bf16 (every call; ws is poisoned)
// ---------------------------------------------------------------------------
__global__ __launch_bounds__(256) void wconv_kernel(
    const float* __restrict__ w1, int n1, const float* __restrict__ w2, int n2,
    ushortT* __restrict__ o1, ushortT* __restrict__ o2)
{
    int i = blockIdx.x * 256 + threadIdx.x;
    if (i < n1) { o1[i] = f2bf(w1[i]); return; }
    i -= n1;
    if (i < n2) o2[i] = f2bf(w2[i]);
}

// ---------------------------------------------------------------------------
// LayerNorm: one wave per row of 384; block = 4 rows. Writes bf16.
// ---------------------------------------------------------------------------
__global__ __launch_bounds__(256) void ln_kernel(
    const float* __restrict__ x, const float* __restrict__ w,
    const float* __restrict__ b, ushortT* __restrict__ xn,
    int row0, int nrows)
{
    int r = blockIdx.x * 4 + (threadIdx.x >> 6);
    if (r >= nrows) return;
    int lane = threadIdx.x & 63;
    const float* xr = x + (size_t)(row0 + r) * DM_;
    float v[6];
    float s = 0.0f;
#pragma unroll
    for (int i = 0; i < 6; i++) { v[i] = xr[lane + 64 * i]; s += v[i]; }
#pragma unroll
    for (int o = 32; o > 0; o >>= 1) s += __shfl_down(s, o, 64);
    s = __shfl(s, 0, 64);
    float mu = s * (1.0f / DM_);
    float q = 0.0f;
#pragma unroll
    for (int i = 0; i < 6; i++) { float d = v[i] - mu; q += d * d; }
#pragma unroll
    for (int o = 32; o > 0; o >>= 1) q += __shfl_down(q, o, 64);
    q = __shfl(q, 0, 64);
    float rstd = rsqrtf(q * (1.0f / DM_) + 1e-5f);
    ushortT* outp = xn + (size_t)r * DM_;
#pragma unroll
    for (int i = 0; i < 6; i++) {
        int c = lane + 64 * i;
        outp[c] = f2bf((v[i] - mu) * rstd * w[c] + b[c]);
    }
}

// ---------------------------------------------------------------------------
// bf16 MFMA GEMM: C[M x N] = [Aa | Ab] [M x Ktot] * Wcat^T (+ R)
// Aa, Ab are bf16 [M][Khalf]; W is bf16 [N][Khalf] applied to BOTH halves
// (out_proj: W*(yf+yb) == W*yf + W*yb as K-concat). Ab==null -> Ktot=Khalf.
// BM=BN=128, BK=32; 256 thr = 4 waves, each wave a 64x64 quadrant.
// M%128==0, N%128==0, Khalf%32==0 required.
// mfma_f32_16x16x32_bf16 layouts (HW-verified, guide §3):
//   a-frag lane l: A[m=l&15][k=(l>>4)*8+j]   (8 contiguous k)
//   b-frag lane l: B[k=(l>>4)*8+j][n=l&15] = W[n][k]  (8 contiguous k)
//   c/d   lane l, reg r: D[row=(l>>4)*4+r][col=l&15]
// ---------------------------------------------------------------------------
__global__ __launch_bounds__(256) void gemm_bf16_kernel(
    const ushortT* __restrict__ Aa, const ushortT* __restrict__ Ab_,
    const ushortT* __restrict__ W, const float* __restrict__ R,
    float* __restrict__ C, int M, int N, int Khalf)
{
    __shared__ ushortT As[128 * 40];   // 128 rows x 32 k, stride 40 (bank-spread)
    __shared__ ushortT Ws[128 * 40];
    int tid = threadIdx.x;
    int bm = blockIdx.x * 128, bn = blockIdx.y * 128;
    int wave = tid >> 6, lane = tid & 63;
    int wm = wave & 1, wn = wave >> 1;
    f32x4 acc[4][4] = {};
    int Ktot = Ab_ ? 2 * Khalf : Khalf;

    int srow = tid >> 3;            // 0..31 staging row group
    int sc4 = (tid & 7) * 4;        // ushort col 0,4,..,28

    for (int k0 = 0; k0 < Ktot; k0 += 32) {
        const ushortT* Asrc = (k0 < Khalf) ? Aa : Ab_;
        int ka = (k0 < Khalf) ? k0 : (k0 - Khalf);
        __syncthreads();
#pragma unroll
        for (int i = 0; i < 4; i++) {
            int row = srow + 32 * i;
            *(ushort4*)&As[row * 40 + sc4] =
                *(const ushort4*)(Asrc + (size_t)(bm + row) * Khalf + ka + sc4);
            *(ushort4*)&Ws[row * 40 + sc4] =
                *(const ushort4*)(W + (size_t)(bn + row) * Khalf + ka + sc4);
        }
        __syncthreads();
        int mbase = (wm * 64 + (lane & 15)) * 40 + (lane >> 4) * 8;
        int nbase = (wn * 64 + (lane & 15)) * 40 + (lane >> 4) * 8;
        bf16x8 af[4], bfr[4];
#pragma unroll
        for (int t = 0; t < 4; t++) {
            af[t]  = *(bf16x8*)&As[mbase + t * 16 * 40];
            bfr[t] = *(bf16x8*)&Ws[nbase + t * 16 * 40];
        }
#pragma unroll
        for (int mi = 0; mi < 4; mi++)
#pragma unroll
            for (int ni = 0; ni < 4; ni++)
                acc[mi][ni] = __builtin_amdgcn_mfma_f32_16x16x32_bf16(
                    af[mi], bfr[ni], acc[mi][ni], 0, 0, 0);
    }

#pragma unroll
    for (int mi = 0; mi < 4; mi++) {
        int row = bm + wm * 64 + 16 * mi + (lane >> 4) * 4;
#pragma unroll
        for (int ni = 0; ni < 4; ni++) {
            int col = bn + wn * 64 + 16 * ni + (lane & 15);
#pragma unroll
            for (int r = 0; r < 4; r++) {
                size_t o = (size_t)(row + r) * N + col;
                float v = acc[mi][ni][r];
                if (R) v += R[o];
                C[o] = v;
            }
        }
    }
}

// ---------------------------------------------------------------------------
// Causal depthwise conv (K=4) + silu, both directions in one launch.
// ---------------------------------------------------------------------------
__global__ __launch_bounds__(256) void conv_kernel(
    const float* __restrict__ xz,
    const float* __restrict__ wf, const float* __restrict__ bf,
    const float* __restrict__ wb, const float* __restrict__ bb,
    float* __restrict__ xhf, float* __restrict__ xhb, int gB)
{
    int idx = blockIdx.x * 256 + threadIdx.x;
    int total = gB * LN_ * DI_;
    int dir = 0;
    if (idx >= total) { idx -= total; dir = 1; }
    int d = idx % DI_;
    int l = (idx / DI_) & (LN_ - 1);
    int b = idx / (DI_ * LN_);
    const float* w = dir ? wb : wf;
    float s = (dir ? bb : bf)[d];
#pragma unroll
    for (int k = 0; k < 4; k++) {
        int j = l - 3 + k;
        if (j < 0) continue;
        int ls = dir ? (LN_ - 1 - j) : j;
        s += w[d * 4 + k] * xz[((size_t)(b * LN_ + ls)) * (2 * DI_) + d];
    }
    float* xh = dir ? xhb : xhf;
    xh[((size_t)(b * LN_ + l)) * DI_ + d] = silu_f(s);
}

// ---------------------------------------------------------------------------
// fp32 GEMM for x_proj (N=56), both directions via blockIdx.y.
// BM=128, BK=16, TM=8, TN=4.
// ---------------------------------------------------------------------------
__global__ __launch_bounds__(256) void xproj_gemm_kernel(
    const float* __restrict__ Af, const float* __restrict__ Wf, float* __restrict__ Cf,
    const float* __restrict__ Ab, const float* __restrict__ Wb, float* __restrict__ Cb,
    int M)
{
    const int N = NDBC_, K = DI_;
    const float* A = blockIdx.y ? Ab : Af;
    const float* W = blockIdx.y ? Wb : Wf;
    float* C = blockIdx.y ? Cb : Cf;
    __shared__ float As[16][128 + 4];
    __shared__ float Ws2[16][64 + 4];
    int tid = threadIdx.x;
    int bm = blockIdx.x * 128;
    int tx = tid & 15, ty = tid >> 4;
    float acc[8][4] = {};
    int ar = tid >> 2, ak = (tid & 3) * 4;

    for (int k0 = 0; k0 < K; k0 += 16) {
#pragma unroll
        for (int h = 0; h < 2; h++) {
            int row = bm + ar + 64 * h;
            float4 v = *(const float4*)(A + (size_t)row * K + k0 + ak);
            As[ak + 0][ar + 64 * h] = v.x;
            As[ak + 1][ar + 64 * h] = v.y;
            As[ak + 2][ar + 64 * h] = v.z;
            As[ak + 3][ar + 64 * h] = v.w;
        }
        {
            float4 v = make_float4(0.f, 0.f, 0.f, 0.f);
            if (ar < N) v = *(const float4*)(W + (size_t)ar * K + k0 + ak);
            Ws2[ak + 0][ar] = v.x;
            Ws2[ak + 1][ar] = v.y;
            Ws2[ak + 2][ar] = v.z;
            Ws2[ak + 3][ar] = v.w;
        }
        __syncthreads();
#pragma unroll
        for (int kk = 0; kk < 16; kk++) {
            float4 a0 = *(float4*)&As[kk][ty * 8];
            float4 a1 = *(float4*)&As[kk][ty * 8 + 4];
            float4 b0 = *(float4*)&Ws2[kk][tx * 4];
            float a[8] = {a0.x, a0.y, a0.z, a0.w, a1.x, a1.y, a1.z, a1.w};
            float w4[4] = {b0.x, b0.y, b0.z, b0.w};
#pragma unroll
            for (int i = 0; i < 8; i++)
#pragma unroll
                for (int j = 0; j < 4; j++)
                    acc[i][j] = fmaf(a[i], w4[j], acc[i][j]);
        }
        __syncthreads();
    }
    int col = tx * 4;
    if (col < N) {
#pragma unroll
        for (int i = 0; i < 8; i++) {
            int row = bm + ty * 8 + i;
            *(float4*)(C + (size_t)row * N + col) =
                make_float4(acc[i][0], acc[i][1], acc[i][2], acc[i][3]);
        }
    }
}

// ---------------------------------------------------------------------------
// Chunked selective scan.
// Phase 1: per-chunk local scan (h0=0) -> local final state + chunk decay.
// Phase 2: cross-chunk state scan (16 steps, massively parallel).
// Phase 3: per-chunk scan seeded with true incoming state -> gated bf16 y.
// delta = softplus(dbc[0:24] @ dt_w^T + dt_b) computed inline (fused).
// grid for 1/3: dir(2) x gB x dchunk(3) x chunk(NC_), 256 thr (one per d).
// ---------------------------------------------------------------------------
__global__ __launch_bounds__(256) void scan1_kernel(
    const float* __restrict__ xhf, const float* __restrict__ dbcf,
    const float* __restrict__ dtwf, const float* __restrict__ dtbf,
    const float* __restrict__ alogf,
    const float* __restrict__ xhb, const float* __restrict__ dbcb,
    const float* __restrict__ dtwb, const float* __restrict__ dtbb,
    const float* __restrict__ alogb,
    float* __restrict__ hs1, float* __restrict__ dec, int gB)
{
    int bid = blockIdx.x;
    int c = bid % NC_; bid /= NC_;
    int dchunk = bid % 3; bid /= 3;
    int b = bid % gB;
    int dir = bid / gB;
    int d = dchunk * 256 + threadIdx.x;

    const float* xh  = dir ? xhb  : xhf;
    const float* dbc = dir ? dbcb : dbcf;
    const float* dtw = (dir ? dtwb : dtwf) + d * RDT_;
    float dtb        = (dir ? dtbb : dtbf)[d];
    const float* alog = dir ? alogb : alogf;

    float An[NS_];
#pragma unroll
    for (int n = 0; n < NS_; n++) An[n] = -__expf(alog[d * NS_ + n]);
    float wrow[RDT_];
#pragma unroll
    for (int r = 0; r < RDT_; r++) wrow[r] = dtw[r];

    __shared__ float sdbc[LC_ * NDBC_];
    size_t rb = (size_t)b * LN_ + c * LC_;
#pragma unroll
    for (int i = 0; i < 4; i++) {
        int idx = threadIdx.x + 256 * i;
        if (idx < LC_ * NDBC_ / 4) {
            int row = idx / 14, c4 = (idx % 14) * 4;
            *(float4*)&sdbc[row * NDBC_ + c4] =
                *(const float4*)(dbc + (rb + row) * NDBC_ + c4);
        }
    }
    __syncthreads();

    float h[NS_];
#pragma unroll
    for (int n = 0; n < NS_; n++) h[n] = 0.0f;
    float S = 0.0f;

    for (int lr = 0; lr < LC_; lr++) {
        const float* rowp = &sdbc[lr * NDBC_];
        float s = dtb;
#pragma unroll
        for (int r = 0; r < RDT_; r++) s = fmaf(rowp[r], wrow[r], s);
        float dt = softplus_f(s);
        S += dt;
        float u = xh[(rb + lr) * DI_ + d];
        float du = dt * u;
#pragma unroll
        for (int n = 0; n < NS_; n++)
            h[n] = fmaf(h[n], __expf(dt * An[n]), du * rowp[RDT_ + n]);
    }
    size_t si = ((((size_t)dir * gB + b) * NC_ + c) * DI_ + d) * NS_;
#pragma unroll
    for (int n = 0; n < NS_; n++) {
        hs1[si + n] = h[n];
        dec[si + n] = __expf(An[n] * S);   // prod exp(dt*A) == exp(A*sum dt)
    }
}

__global__ __launch_bounds__(256) void scan2_kernel(
    const float* __restrict__ hs1, const float* __restrict__ dec,
    float* __restrict__ hin, int gB)
{
    int e = blockIdx.x * 256 + threadIdx.x;
    int n = e & 15; int e2 = e >> 4;
    int d = e2 % DI_; e2 /= DI_;
    int b = e2 % gB; int dir = e2 / gB;
    size_t base = (((size_t)dir * gB + b) * NC_) * DI_ * NS_ + (size_t)d * NS_ + n;
    float h = 0.0f;
    const size_t cs = (size_t)DI_ * NS_;
    for (int c = 0; c < NC_; c++) {
        size_t idx = base + c * cs;
        hin[idx] = h;
        h = fmaf(h, dec[idx], hs1[idx]);
    }
}

__global__ __launch_bounds__(256) void scan3_kernel(
    const float* __restrict__ xhf, const float* __restrict__ dbcf,
    const float* __restrict__ dtwf, const float* __restrict__ dtbf,
    const float* __restrict__ alogf, const float* __restrict__ dvf,
    const float* __restrict__ xhb, const float* __restrict__ dbcb,
    const float* __restrict__ dtwb, const float* __restrict__ dtbb,
    const float* __restrict__ alogb, const float* __restrict__ dvb,
    const float* __restrict__ hin, const float* __restrict__ xz,
    ushortT* __restrict__ yf, ushortT* __restrict__ yb, int gB)
{
    int bid = blockIdx.x;
    int c = bid % NC_; bid /= NC_;
    int dchunk = bid % 3; bid /= 3;
    int b = bid % gB;
    int dir = bid / gB;
    int d = dchunk * 256 + threadIdx.x;

    const float* xh  = dir ? xhb  : xhf;
    const float* dbc = dir ? dbcb : dbcf;
    const float* dtw = (dir ? dtwb : dtwf) + d * RDT_;
    float dtb        = (dir ? dtbb : dtbf)[d];
    const float* alog = dir ? alogb : alogf;
    float Dd         = (dir ? dvb : dvf)[d];
    ushortT* y       = dir ? yb : yf;

    float An[NS_];
#pragma unroll
    for (int n = 0; n < NS_; n++) An[n] = -__expf(alog[d * NS_ + n]);
    float wrow[RDT_];
#pragma unroll
    for (int r = 0; r < RDT_; r++) wrow[r] = dtw[r];

    __shared__ float sdbc[LC_ * NDBC_];
    size_t rb = (size_t)b * LN_ + c * LC_;
#pragma unroll
    for (int i = 0; i < 4; i++) {
        int idx = threadIdx.x + 256 * i;
        if (idx < LC_ * NDBC_ / 4) {
            int row = idx / 14, c4 = (idx % 14) * 4;
            *(float4*)&sdbc[row * NDBC_ + c4] =
                *(const float4*)(dbc + (rb + row) * NDBC_ + c4);
        }
    }
    __syncthreads();

    size_t si = ((((size_t)dir * gB + b) * NC_ + c) * DI_ + d) * NS_;
    float h[NS_];
#pragma unroll
    for (int n = 0; n < NS_; n++) h[n] = hin[si + n];

    for (int lr = 0; lr < LC_; lr++) {
        const float* rowp = &sdbc[lr * NDBC_];
        float s = dtb;
#pragma unroll
        for (int r = 0; r < RDT_; r++) s = fmaf(rowp[r], wrow[r], s);
        float dt = softplus_f(s);
        float u = xh[(rb + lr) * DI_ + d];
        float du = dt * u;
        float yv = 0.0f;
#pragma unroll
        for (int n = 0; n < NS_; n++) {
            h[n] = fmaf(h[n], __expf(dt * An[n]), du * rowp[RDT_ + n]);
            yv = fmaf(h[n], rowp[RDT_ + NS_ + n], yv);
        }
        yv = fmaf(u, Dd, yv);
        int l = c * LC_ + lr;
        int lo = dir ? (LN_ - 1 - l) : l;
        float z = xz[((size_t)b * LN_ + lo) * (2 * DI_) + DI_ + d];
        y[((size_t)b * LN_ + lo) * DI_ + d] = f2bf(yv * silu_f(z));
    }
}

// ---------------------------------------------------------------------------
// Host launcher.
// ---------------------------------------------------------------------------
extern "C" void kernel_launch(void* const* d_in, const int* in_sizes, int n_in,
                              void* d_out, int out_size, void* d_ws, size_t ws_size,
                              hipStream_t stream)
{
    const float* x         = (const float*)d_in[0];
    const float* ln_w      = (const float*)d_in[1];
    const float* ln_b      = (const float*)d_in[2];
    const float* in_proj_w = (const float*)d_in[3];
    const float* out_proj_w= (const float*)d_in[4];
    const float* conv_wf   = (const float*)d_in[5];
    const float* conv_bf   = (const float*)d_in[6];
    const float* xproj_f   = (const float*)d_in[7];
    const float* dt_wf     = (const float*)d_in[8];
    const float* dt_bf     = (const float*)d_in[9];
    const float* alog_f    = (const float*)d_in[10];
    const float* dv_f      = (const float*)d_in[11];
    const float* conv_wb   = (const float*)d_in[12];
    const float* conv_bb   = (const float*)d_in[13];
    const float* xproj_b   = (const float*)d_in[14];
    const float* dt_wb     = (const float*)d_in[15];
    const float* dt_bb     = (const float*)d_in[16];
    const float* alog_b    = (const float*)d_in[17];
    const float* dv_b      = (const float*)d_in[18];
    float* outp = (float*)d_out;

    const int n_w1 = 2 * DI_ * DM_;   // in_proj  1536x384
    const int n_w2 = DM_ * DI_;       // out_proj 384x768

    uint8_t* base = (uint8_t*)d_ws;
    size_t off = 0;
    auto alloc = [&](size_t nbytes) {
        uint8_t* r = base + off;
        off = (off + nbytes + 255) & ~(size_t)255;
        return r;
    };
    ushortT* WbIn  = (ushortT*)alloc((size_t)n_w1 * 2);
    ushortT* WbOut = (ushortT*)alloc((size_t)n_w2 * 2);
    size_t fixed_bytes = off;

    // per-batch workspace ~20.7 MiB
    size_t per_b_bytes = 22ull * 1024 * 1024;
    int g = BN_;
    while (g > 1 && fixed_bytes + (size_t)g * per_b_bytes + (1ull << 20) > ws_size) g >>= 1;

    wconv_kernel<<<(n_w1 + n_w2 + 255) / 256, 256, 0, stream>>>(
        in_proj_w, n_w1, out_proj_w, n_w2, WbIn, WbOut);

    for (int b0 = 0; b0 < BN_; b0 += g) {
        int rows = g * LN_;
        off = fixed_bytes;
        ushortT* XNb = (ushortT*)alloc((size_t)rows * DM_ * 2);
        float* XZ    = (float*)alloc((size_t)rows * 2 * DI_ * 4);
        float* XHf   = (float*)alloc((size_t)rows * DI_ * 4);
        float* XHb   = (float*)alloc((size_t)rows * DI_ * 4);
        float* DBCf  = (float*)alloc((size_t)rows * NDBC_ * 4);
        float* DBCb  = (float*)alloc((size_t)rows * NDBC_ * 4);
        size_t st_n  = (size_t)2 * g * NC_ * DI_ * NS_;
        float* HS1   = (float*)alloc(st_n * 4);
        float* DEC   = (float*)alloc(st_n * 4);
        float* HIN   = (float*)alloc(st_n * 4);
        ushortT* Yf  = (ushortT*)alloc((size_t)rows * DI_ * 2);
        ushortT* Yb  = (ushortT*)alloc((size_t)rows * DI_ * 2);
        int row0 = b0 * LN_;

        ln_kernel<<<rows / 4, 256, 0, stream>>>(x, ln_w, ln_b, XNb, row0, rows);

        gemm_bf16_kernel<<<dim3(rows / 128, (2 * DI_) / 128), 256, 0, stream>>>(
            XNb, nullptr, WbIn, nullptr, XZ, rows, 2 * DI_, DM_);

        conv_kernel<<<(2 * rows * DI_) / 256, 256, 0, stream>>>(
            XZ, conv_wf, conv_bf, conv_wb, conv_bb, XHf, XHb, g);

        xproj_gemm_kernel<<<dim3(rows / 128, 2), 256, 0, stream>>>(
            XHf, xproj_f, DBCf, XHb, xproj_b, DBCb, rows);

        scan1_kernel<<<2 * g * 3 * NC_, 256, 0, stream>>>(
            XHf, DBCf, dt_wf, dt_bf, alog_f,
            XHb, DBCb, dt_wb, dt_bb, alog_b, HS1, DEC, g);

        scan2_kernel<<<(2 * g * DI_ * NS_) / 256, 256, 0, stream>>>(HS1, DEC, HIN, g);

        scan3_kernel<<<2 * g * 3 * NC_, 256, 0, stream>>>(
            XHf, DBCf, dt_wf, dt_bf, alog_f, dv_f,
            XHb, DBCb, dt_wb, dt_bb, alog_b, dv_b,
            HIN, XZ, Yf, Yb, g);

        gemm_bf16_kernel<<<dim3(rows / 128, DM_ / 128), 256, 0, stream>>>(
            Yf, Yb, WbOut, x + (size_t)row0 * DM_,
            outp + (size_t)row0 * DM_, rows, DM_, DI_);
    }
}

// Round 3
// 759.827 us; speedup vs baseline: 2.7673x; 1.2202x over previous
//
#include <hip/hip_runtime.h>
#include <cstdint>
#include <cstddef>

// Problem constants
#define BN_   16
#define LN_   1024
#define DM_   384
#define DI_   768
#define NS_   16
#define RDT_  24
#define NDBC_ 56
#define NC_   16
#define LC_   64

typedef unsigned short ushortT;
typedef short bf16x8 __attribute__((ext_vector_type(8)));
typedef float f32x4 __attribute__((ext_vector_type(4)));

typedef __attribute__((address_space(3))) uint32_t lds_u32_t;
typedef __attribute__((address_space(1))) const uint32_t glb_u32_t;

static __device__ __forceinline__ void stage16(const void* g, void* lds) {
    // async global->LDS, 16B per lane; LDS dest = wave-uniform base + lane*16
    __builtin_amdgcn_global_load_lds(
        (glb_u32_t*)(uintptr_t)g,
        (lds_u32_t*)(uint32_t)(uintptr_t)lds,
        16, 0, 0);
}

static __device__ __forceinline__ float silu_f(float x) {
    return x / (1.0f + __expf(-x));
}
static __device__ __forceinline__ float softplus_f(float x) {
    return (x > 20.0f) ? x : log1pf(__expf(x));
}
static __device__ __forceinline__ ushortT f2bf(float f) {
    union { float f; uint32_t u; } v; v.f = f;
    uint32_t u = v.u;
    uint32_t r = u + 0x7fffu + ((u >> 16) & 1u);
    return (ushortT)(r >> 16);
}

// ---------------------------------------------------------------------------
// fp32 -> bf16 weight conversion (in_proj, out_proj)
// ---------------------------------------------------------------------------
__global__ __launch_bounds__(256) void wconv_kernel(
    const float* __restrict__ w1, int n1, const float* __restrict__ w2, int n2,
    ushortT* __restrict__ o1, ushortT* __restrict__ o2)
{
    int i = blockIdx.x * 256 + threadIdx.x;
    if (i < n1) { o1[i] = f2bf(w1[i]); return; }
    i -= n1;
    if (i < n2) o2[i] = f2bf(w2[i]);
}

// ---------------------------------------------------------------------------
// LayerNorm: one wave per row of 384; block = 4 rows. Writes bf16.
// ---------------------------------------------------------------------------
__global__ __launch_bounds__(256) void ln_kernel(
    const float* __restrict__ x, const float* __restrict__ w,
    const float* __restrict__ b, ushortT* __restrict__ xn,
    int row0, int nrows)
{
    int r = blockIdx.x * 4 + (threadIdx.x >> 6);
    if (r >= nrows) return;
    int lane = threadIdx.x & 63;
    const float* xr = x + (size_t)(row0 + r) * DM_;
    float v[6];
    float s = 0.0f;
#pragma unroll
    for (int i = 0; i < 6; i++) { v[i] = xr[lane + 64 * i]; s += v[i]; }
#pragma unroll
    for (int o = 32; o > 0; o >>= 1) s += __shfl_down(s, o, 64);
    s = __shfl(s, 0, 64);
    float mu = s * (1.0f / DM_);
    float q = 0.0f;
#pragma unroll
    for (int i = 0; i < 6; i++) { float d = v[i] - mu; q += d * d; }
#pragma unroll
    for (int o = 32; o > 0; o >>= 1) q += __shfl_down(q, o, 64);
    q = __shfl(q, 0, 64);
    float rstd = rsqrtf(q * (1.0f / DM_) + 1e-5f);
    ushortT* outp = xn + (size_t)r * DM_;
#pragma unroll
    for (int i = 0; i < 6; i++) {
        int c = lane + 64 * i;
        outp[c] = f2bf((v[i] - mu) * rstd * w[c] + b[c]);
    }
}

// ---------------------------------------------------------------------------
// bf16 MFMA GEMM (m97-style): C[M x N] = [Aa | Ab] * W^T (+ R)
// Tight LDS layout (32 ushort = 64B per row), global_load_lds width-16
// staging, 2-barrier K-loop. 256 thr = 4 waves in WR x WC wave grid.
// mfma_f32_16x16x32_bf16 layouts (HW-verified):
//   a/b frag lane l: [m|n = l&15][k = (l>>4)*8 + j]  (8 contiguous k)
//   c/d  lane l reg r: D[row=(l>>4)*4+r][col=l&15]
// ---------------------------------------------------------------------------
template <int BM, int BN, int WR, int WC, bool CAT, bool RES>
__global__ __launch_bounds__(256) void gemm_mfma(
    const ushortT* __restrict__ Aa, const ushortT* __restrict__ Ab_,
    const ushortT* __restrict__ W, const float* __restrict__ R,
    float* __restrict__ C, int M, int N, int Khalf)
{
    constexpr int WTM = BM / WR;
    constexpr int WTN = BN / WC;
    constexpr int FM = WTM / 16;
    constexpr int FN = WTN / 16;
    __shared__ ushortT As[BM * 32];
    __shared__ ushortT Ws[BN * 32];
    int tid = threadIdx.x;
    int bm = blockIdx.x * BM, bn = blockIdx.y * BN;
    int wave = tid >> 6, lane = tid & 63;
    int wm = wave % WR, wn = wave / WR;
    f32x4 acc[FM][FN] = {};
    int Ktot = CAT ? 2 * Khalf : Khalf;
    int lrow = lane >> 2;        // 0..15 within 16-row chunk
    int lk = (lane & 3) * 8;     // bf16 k-offset (16B granules)

    for (int k0 = 0; k0 < Ktot; k0 += 32) {
        const ushortT* Asrc = (!CAT || k0 < Khalf) ? Aa : Ab_;
        int ka = (!CAT || k0 < Khalf) ? k0 : (k0 - Khalf);
        __syncthreads();
#pragma unroll
        for (int c = 0; c < BM / 64; c++) {
            int ch = c * 4 + wave;
            int row = ch * 16 + lrow;
            stage16(Asrc + (size_t)(bm + row) * Khalf + ka + lk, &As[ch * 16 * 32]);
        }
#pragma unroll
        for (int c = 0; c < BN / 64; c++) {
            int ch = c * 4 + wave;
            int row = ch * 16 + lrow;
            stage16(W + (size_t)(bn + row) * Khalf + ka + lk, &Ws[ch * 16 * 32]);
        }
        __syncthreads();
        int mb = (wm * WTM + (lane & 15)) * 32 + (lane >> 4) * 8;
        int nb = (wn * WTN + (lane & 15)) * 32 + (lane >> 4) * 8;
        bf16x8 af[FM], bfr[FN];
#pragma unroll
        for (int mi = 0; mi < FM; mi++) af[mi] = *(bf16x8*)&As[mb + mi * 16 * 32];
#pragma unroll
        for (int ni = 0; ni < FN; ni++) bfr[ni] = *(bf16x8*)&Ws[nb + ni * 16 * 32];
#pragma unroll
        for (int mi = 0; mi < FM; mi++)
#pragma unroll
            for (int ni = 0; ni < FN; ni++)
                acc[mi][ni] = __builtin_amdgcn_mfma_f32_16x16x32_bf16(
                    af[mi], bfr[ni], acc[mi][ni], 0, 0, 0);
    }

#pragma unroll
    for (int mi = 0; mi < FM; mi++) {
        int row = bm + wm * WTM + 16 * mi + (lane >> 4) * 4;
#pragma unroll
        for (int ni = 0; ni < FN; ni++) {
            int col = bn + wn * WTN + 16 * ni + (lane & 15);
#pragma unroll
            for (int r = 0; r < 4; r++) {
                size_t o = (size_t)(row + r) * N + col;
                float v = acc[mi][ni][r];
                if (RES) v += R[o];
                C[o] = v;
            }
        }
    }
}

// ---------------------------------------------------------------------------
// Causal depthwise conv (K=4) + silu, float4 over d, both dirs one launch.
// ---------------------------------------------------------------------------
__global__ __launch_bounds__(256) void conv_kernel(
    const float* __restrict__ xz,
    const float* __restrict__ wf, const float* __restrict__ bf,
    const float* __restrict__ wb, const float* __restrict__ bb,
    float* __restrict__ xhf, float* __restrict__ xhb, int gB)
{
    const int DQ = DI_ / 4;  // 192
    int idx = blockIdx.x * 256 + threadIdx.x;
    int perdir = gB * LN_ * DQ;
    int dir = 0;
    if (idx >= perdir) { idx -= perdir; dir = 1; }
    int dq = idx % DQ;
    int l = (idx / DQ) & (LN_ - 1);
    int b = idx / (DQ * LN_);
    int d4 = dq * 4;
    const float4* w4 = (const float4*)(dir ? wb : wf);
    float4 wv0 = w4[d4 + 0], wv1 = w4[d4 + 1], wv2 = w4[d4 + 2], wv3 = w4[d4 + 3];
    const float* wp0 = (const float*)&wv0;
    const float* wp1 = (const float*)&wv1;
    const float* wp2 = (const float*)&wv2;
    const float* wp3 = (const float*)&wv3;
    float4 bias = *(const float4*)((dir ? bb : bf) + d4);
    float s0 = bias.x, s1 = bias.y, s2 = bias.z, s3 = bias.w;
#pragma unroll
    for (int k = 0; k < 4; k++) {
        int j = l - 3 + k;
        if (j < 0) continue;
        int ls = dir ? (LN_ - 1 - j) : j;
        float4 xv = *(const float4*)(xz + ((size_t)(b * LN_ + ls)) * (2 * DI_) + d4);
        s0 = fmaf(xv.x, wp0[k], s0);
        s1 = fmaf(xv.y, wp1[k], s1);
        s2 = fmaf(xv.z, wp2[k], s2);
        s3 = fmaf(xv.w, wp3[k], s3);
    }
    float* xh = dir ? xhb : xhf;
    float4 o = make_float4(silu_f(s0), silu_f(s1), silu_f(s2), silu_f(s3));
    *(float4*)(xh + ((size_t)(b * LN_ + l)) * DI_ + d4) = o;
}

// ---------------------------------------------------------------------------
// fp32 GEMM for x_proj (N=56), BM=64, BN=64 (8 cols wasted), dirs via grid.y.
// ---------------------------------------------------------------------------
__global__ __launch_bounds__(256) void xproj_gemm_kernel(
    const float* __restrict__ Af, const float* __restrict__ Wf, float* __restrict__ Cf,
    const float* __restrict__ Ab, const float* __restrict__ Wb, float* __restrict__ Cb,
    int M)
{
    const int N = NDBC_, K = DI_;
    const float* A = blockIdx.y ? Ab : Af;
    const float* W = blockIdx.y ? Wb : Wf;
    float* C = blockIdx.y ? Cb : Cf;
    __shared__ float As2[16][68];
    __shared__ float Ws2[16][68];
    int tid = threadIdx.x;
    int bm = blockIdx.x * 64;
    int tx = tid & 15, ty = tid >> 4;
    float acc[4][4] = {};
    int ar = tid >> 2;        // 0..63
    int ak = (tid & 3) * 4;   // 0,4,8,12

    for (int k0 = 0; k0 < K; k0 += 16) {
        float4 va = *(const float4*)(A + (size_t)(bm + ar) * K + k0 + ak);
        float4 vw = make_float4(0.f, 0.f, 0.f, 0.f);
        if (ar < N) vw = *(const float4*)(W + (size_t)ar * K + k0 + ak);
        As2[ak + 0][ar] = va.x; As2[ak + 1][ar] = va.y;
        As2[ak + 2][ar] = va.z; As2[ak + 3][ar] = va.w;
        Ws2[ak + 0][ar] = vw.x; Ws2[ak + 1][ar] = vw.y;
        Ws2[ak + 2][ar] = vw.z; Ws2[ak + 3][ar] = vw.w;
        __syncthreads();
#pragma unroll
        for (int kk = 0; kk < 16; kk++) {
            float4 a4 = *(float4*)&As2[kk][ty * 4];
            float4 b4 = *(float4*)&Ws2[kk][tx * 4];
            float aa[4] = {a4.x, a4.y, a4.z, a4.w};
            float bb4[4] = {b4.x, b4.y, b4.z, b4.w};
#pragma unroll
            for (int i = 0; i < 4; i++)
#pragma unroll
                for (int j = 0; j < 4; j++)
                    acc[i][j] = fmaf(aa[i], bb4[j], acc[i][j]);
        }
        __syncthreads();
    }
    if (tx < 14) {  // cols 0..55
#pragma unroll
        for (int i = 0; i < 4; i++) {
            int row = bm + ty * 4 + i;
            *(float4*)(C + (size_t)row * N + tx * 4) =
                make_float4(acc[i][0], acc[i][1], acc[i][2], acc[i][3]);
        }
    }
}

// ---------------------------------------------------------------------------
// Chunked selective scan; dt-projection fused; A=-(n+1) power fast path
// (guarded by runtime check, general path kept).
// ---------------------------------------------------------------------------
__global__ __launch_bounds__(256) void scan1_kernel(
    const float* __restrict__ xhf, const float* __restrict__ dbcf,
    const float* __restrict__ dtwf, const float* __restrict__ dtbf,
    const float* __restrict__ alogf,
    const float* __restrict__ xhb, const float* __restrict__ dbcb,
    const float* __restrict__ dtwb, const float* __restrict__ dtbb,
    const float* __restrict__ alogb,
    float* __restrict__ hs1, float* __restrict__ dec, int gB)
{
    int bid = blockIdx.x;
    int c = bid % NC_; bid /= NC_;
    int dchunk = bid % 3; bid /= 3;
    int b = bid % gB;
    int dir = bid / gB;
    int d = dchunk * 256 + threadIdx.x;

    const float* xh  = dir ? xhb  : xhf;
    const float* dbc = dir ? dbcb : dbcf;
    const float* dtw = (dir ? dtwb : dtwf) + d * RDT_;
    float dtb        = (dir ? dtbb : dtbf)[d];
    const float* alog = dir ? alogb : alogf;

    float An[NS_];
#pragma unroll
    for (int n = 0; n < NS_; n++) An[n] = -__expf(alog[d * NS_ + n]);
    float a1 = An[0];
    bool pk = true;
#pragma unroll
    for (int n = 0; n < NS_; n++)
        pk = pk && (fabsf(An[n] - (float)(n + 1) * a1) <=
                    1e-3f * (float)(n + 1) * fabsf(a1) + 1e-6f);
    pk = (bool)__all((int)pk);

    float wrow[RDT_];
#pragma unroll
    for (int r = 0; r < RDT_; r++) wrow[r] = dtw[r];

    __shared__ float sdbc[LC_ * NDBC_];
    size_t rb = (size_t)b * LN_ + c * LC_;
#pragma unroll
    for (int i = 0; i < 4; i++) {
        int idx = threadIdx.x + 256 * i;
        if (idx < LC_ * NDBC_ / 4) {
            int row = idx / 14, c4 = (idx % 14) * 4;
            *(float4*)&sdbc[row * NDBC_ + c4] =
                *(const float4*)(dbc + (rb + row) * NDBC_ + c4);
        }
    }
    __syncthreads();

    float h[NS_];
#pragma unroll
    for (int n = 0; n < NS_; n++) h[n] = 0.0f;
    float S = 0.0f;

    if (pk) {
        for (int lr = 0; lr < LC_; lr++) {
            const float* rowp = &sdbc[lr * NDBC_];
            float s = dtb;
#pragma unroll
            for (int r = 0; r < RDT_; r++) s = fmaf(rowp[r], wrow[r], s);
            float dt = softplus_f(s);
            S += dt;
            float u = xh[(rb + lr) * DI_ + d];
            float du = dt * u;
            float rr = __expf(dt * a1);
            float p = 1.0f;
#pragma unroll
            for (int n = 0; n < NS_; n++) {
                p *= rr;
                h[n] = fmaf(h[n], p, du * rowp[RDT_ + n]);
            }
        }
        float rs = __expf(S * a1);
        float p = 1.0f;
        size_t si = ((((size_t)dir * gB + b) * NC_ + c) * DI_ + d) * NS_;
#pragma unroll
        for (int n = 0; n < NS_; n++) {
            p *= rs;
            hs1[si + n] = h[n];
            dec[si + n] = p;
        }
    } else {
        for (int lr = 0; lr < LC_; lr++) {
            const float* rowp = &sdbc[lr * NDBC_];
            float s = dtb;
#pragma unroll
            for (int r = 0; r < RDT_; r++) s = fmaf(rowp[r], wrow[r], s);
            float dt = softplus_f(s);
            S += dt;
            float u = xh[(rb + lr) * DI_ + d];
            float du = dt * u;
#pragma unroll
            for (int n = 0; n < NS_; n++)
                h[n] = fmaf(h[n], __expf(dt * An[n]), du * rowp[RDT_ + n]);
        }
        size_t si = ((((size_t)dir * gB + b) * NC_ + c) * DI_ + d) * NS_;
#pragma unroll
        for (int n = 0; n < NS_; n++) {
            hs1[si + n] = h[n];
            dec[si + n] = __expf(An[n] * S);
        }
    }
}

__global__ __launch_bounds__(256) void scan2_kernel(
    const float* __restrict__ hs1, const float* __restrict__ dec,
    float* __restrict__ hin, int gB)
{
    int e = blockIdx.x * 256 + threadIdx.x;
    int n = e & 15; int e2 = e >> 4;
    int d = e2 % DI_; e2 /= DI_;
    int b = e2 % gB; int dir = e2 / gB;
    size_t base = (((size_t)dir * gB + b) * NC_) * DI_ * NS_ + (size_t)d * NS_ + n;
    float h = 0.0f;
    const size_t cs = (size_t)DI_ * NS_;
    for (int c = 0; c < NC_; c++) {
        size_t idx = base + c * cs;
        hin[idx] = h;
        h = fmaf(h, dec[idx], hs1[idx]);
    }
}

__global__ __launch_bounds__(256) void scan3_kernel(
    const float* __restrict__ xhf, const float* __restrict__ dbcf,
    const float* __restrict__ dtwf, const float* __restrict__ dtbf,
    const float* __restrict__ alogf, const float* __restrict__ dvf,
    const float* __restrict__ xhb, const float* __restrict__ dbcb,
    const float* __restrict__ dtwb, const float* __restrict__ dtbb,
    const float* __restrict__ alogb, const float* __restrict__ dvb,
    const float* __restrict__ hin, const float* __restrict__ xz,
    ushortT* __restrict__ yf, ushortT* __restrict__ yb, int gB)
{
    int bid = blockIdx.x;
    int c = bid % NC_; bid /= NC_;
    int dchunk = bid % 3; bid /= 3;
    int b = bid % gB;
    int dir = bid / gB;
    int d = dchunk * 256 + threadIdx.x;

    const float* xh  = dir ? xhb  : xhf;
    const float* dbc = dir ? dbcb : dbcf;
    const float* dtw = (dir ? dtwb : dtwf) + d * RDT_;
    float dtb        = (dir ? dtbb : dtbf)[d];
    const float* alog = dir ? alogb : alogf;
    float Dd         = (dir ? dvb : dvf)[d];
    ushortT* y       = dir ? yb : yf;

    float An[NS_];
#pragma unroll
    for (int n = 0; n < NS_; n++) An[n] = -__expf(alog[d * NS_ + n]);
    float a1 = An[0];
    bool pk = true;
#pragma unroll
    for (int n = 0; n < NS_; n++)
        pk = pk && (fabsf(An[n] - (float)(n + 1) * a1) <=
                    1e-3f * (float)(n + 1) * fabsf(a1) + 1e-6f);
    pk = (bool)__all((int)pk);

    float wrow[RDT_];
#pragma unroll
    for (int r = 0; r < RDT_; r++) wrow[r] = dtw[r];

    __shared__ float sdbc[LC_ * NDBC_];
    size_t rb = (size_t)b * LN_ + c * LC_;
#pragma unroll
    for (int i = 0; i < 4; i++) {
        int idx = threadIdx.x + 256 * i;
        if (idx < LC_ * NDBC_ / 4) {
            int row = idx / 14, c4 = (idx % 14) * 4;
            *(float4*)&sdbc[row * NDBC_ + c4] =
                *(const float4*)(dbc + (rb + row) * NDBC_ + c4);
        }
    }
    __syncthreads();

    size_t si = ((((size_t)dir * gB + b) * NC_ + c) * DI_ + d) * NS_;
    float h[NS_];
#pragma unroll
    for (int n = 0; n < NS_; n++) h[n] = hin[si + n];

    if (pk) {
        for (int lr = 0; lr < LC_; lr++) {
            const float* rowp = &sdbc[lr * NDBC_];
            float s = dtb;
#pragma unroll
            for (int r = 0; r < RDT_; r++) s = fmaf(rowp[r], wrow[r], s);
            float dt = softplus_f(s);
            float u = xh[(rb + lr) * DI_ + d];
            float du = dt * u;
            float rr = __expf(dt * a1);
            float p = 1.0f;
            float yv = 0.0f;
#pragma unroll
            for (int n = 0; n < NS_; n++) {
                p *= rr;
                h[n] = fmaf(h[n], p, du * rowp[RDT_ + n]);
                yv = fmaf(h[n], rowp[RDT_ + NS_ + n], yv);
            }
            yv = fmaf(u, Dd, yv);
            int l = c * LC_ + lr;
            int lo = dir ? (LN_ - 1 - l) : l;
            float z = xz[((size_t)b * LN_ + lo) * (2 * DI_) + DI_ + d];
            y[((size_t)b * LN_ + lo) * DI_ + d] = f2bf(yv * silu_f(z));
        }
    } else {
        for (int lr = 0; lr < LC_; lr++) {
            const float* rowp = &sdbc[lr * NDBC_];
            float s = dtb;
#pragma unroll
            for (int r = 0; r < RDT_; r++) s = fmaf(rowp[r], wrow[r], s);
            float dt = softplus_f(s);
            float u = xh[(rb + lr) * DI_ + d];
            float du = dt * u;
            float yv = 0.0f;
#pragma unroll
            for (int n = 0; n < NS_; n++) {
                h[n] = fmaf(h[n], __expf(dt * An[n]), du * rowp[RDT_ + n]);
                yv = fmaf(h[n], rowp[RDT_ + NS_ + n], yv);
            }
            yv = fmaf(u, Dd, yv);
            int l = c * LC_ + lr;
            int lo = dir ? (LN_ - 1 - l) : l;
            float z = xz[((size_t)b * LN_ + lo) * (2 * DI_) + DI_ + d];
            y[((size_t)b * LN_ + lo) * DI_ + d] = f2bf(yv * silu_f(z));
        }
    }
}

// ---------------------------------------------------------------------------
// Host launcher.
// ---------------------------------------------------------------------------
extern "C" void kernel_launch(void* const* d_in, const int* in_sizes, int n_in,
                              void* d_out, int out_size, void* d_ws, size_t ws_size,
                              hipStream_t stream)
{
    const float* x         = (const float*)d_in[0];
    const float* ln_w      = (const float*)d_in[1];
    const float* ln_b      = (const float*)d_in[2];
    const float* in_proj_w = (const float*)d_in[3];
    const float* out_proj_w= (const float*)d_in[4];
    const float* conv_wf   = (const float*)d_in[5];
    const float* conv_bf   = (const float*)d_in[6];
    const float* xproj_f   = (const float*)d_in[7];
    const float* dt_wf     = (const float*)d_in[8];
    const float* dt_bf     = (const float*)d_in[9];
    const float* alog_f    = (const float*)d_in[10];
    const float* dv_f      = (const float*)d_in[11];
    const float* conv_wb   = (const float*)d_in[12];
    const float* conv_bb   = (const float*)d_in[13];
    const float* xproj_b   = (const float*)d_in[14];
    const float* dt_wb     = (const float*)d_in[15];
    const float* dt_bb     = (const float*)d_in[16];
    const float* alog_b    = (const float*)d_in[17];
    const float* dv_b      = (const float*)d_in[18];
    float* outp = (float*)d_out;

    const int n_w1 = 2 * DI_ * DM_;   // in_proj  1536x384
    const int n_w2 = DM_ * DI_;       // out_proj 384x768

    uint8_t* base = (uint8_t*)d_ws;
    size_t off = 0;
    auto alloc = [&](size_t nbytes) {
        uint8_t* r = base + off;
        off = (off + nbytes + 255) & ~(size_t)255;
        return r;
    };
    ushortT* WbIn  = (ushortT*)alloc((size_t)n_w1 * 2);
    ushortT* WbOut = (ushortT*)alloc((size_t)n_w2 * 2);
    size_t fixed_bytes = off;

    size_t per_b_bytes = 22ull * 1024 * 1024;
    int g = BN_;
    while (g > 1 && fixed_bytes + (size_t)g * per_b_bytes + (1ull << 20) > ws_size) g >>= 1;

    wconv_kernel<<<(n_w1 + n_w2 + 255) / 256, 256, 0, stream>>>(
        in_proj_w, n_w1, out_proj_w, n_w2, WbIn, WbOut);

    for (int b0 = 0; b0 < BN_; b0 += g) {
        int rows = g * LN_;
        off = fixed_bytes;
        ushortT* XNb = (ushortT*)alloc((size_t)rows * DM_ * 2);
        float* XZ    = (float*)alloc((size_t)rows * 2 * DI_ * 4);
        float* XHf   = (float*)alloc((size_t)rows * DI_ * 4);
        float* XHb   = (float*)alloc((size_t)rows * DI_ * 4);
        float* DBCf  = (float*)alloc((size_t)rows * NDBC_ * 4);
        float* DBCb  = (float*)alloc((size_t)rows * NDBC_ * 4);
        size_t st_n  = (size_t)2 * g * NC_ * DI_ * NS_;
        float* HS1   = (float*)alloc(st_n * 4);
        float* DEC   = (float*)alloc(st_n * 4);
        float* HIN   = (float*)alloc(st_n * 4);
        ushortT* Yf  = (ushortT*)alloc((size_t)rows * DI_ * 2);
        ushortT* Yb  = (ushortT*)alloc((size_t)rows * DI_ * 2);
        int row0 = b0 * LN_;

        ln_kernel<<<rows / 4, 256, 0, stream>>>(x, ln_w, ln_b, XNb, row0, rows);

        gemm_mfma<128, 128, 2, 2, false, false>
            <<<dim3(rows / 128, (2 * DI_) / 128), 256, 0, stream>>>(
            XNb, nullptr, WbIn, nullptr, XZ, rows, 2 * DI_, DM_);

        conv_kernel<<<(2 * rows * (DI_ / 4)) / 256, 256, 0, stream>>>(
            XZ, conv_wf, conv_bf, conv_wb, conv_bb, XHf, XHb, g);

        xproj_gemm_kernel<<<dim3(rows / 64, 2), 256, 0, stream>>>(
            XHf, xproj_f, DBCf, XHb, xproj_b, DBCb, rows);

        scan1_kernel<<<2 * g * 3 * NC_, 256, 0, stream>>>(
            XHf, DBCf, dt_wf, dt_bf, alog_f,
            XHb, DBCb, dt_wb, dt_bb, alog_b, HS1, DEC, g);

        scan2_kernel<<<(2 * g * DI_ * NS_) / 256, 256, 0, stream>>>(HS1, DEC, HIN, g);

        scan3_kernel<<<2 * g * 3 * NC_, 256, 0, stream>>>(
            XHf, DBCf, dt_wf, dt_bf, alog_f, dv_f,
            XHb, DBCb, dt_wb, dt_bb, alog_b, dv_b,
            HIN, XZ, Yf, Yb, g);

        gemm_mfma<64, 128, 1, 4, true, true>
            <<<dim3(rows / 64, DM_ / 128), 256, 0, stream>>>(
            Yf, Yb, WbOut, x + (size_t)row0 * DM_,
            outp + (size_t)row0 * DM_, rows, DM_, DI_);
    }
}

// Round 4
// 567.255 us; speedup vs baseline: 3.7067x; 1.3395x over previous
//
#include <hip/hip_runtime.h>
#include <cstdint>
#include <cstddef>

// Problem constants
#define BN_   16
#define LN_   1024
#define DM_   384
#define DI_   768
#define NS_   16
#define RDT_  24
#define NDBC_ 56
#define NDBCP 64     // padded dbc stride
#define NC_   16
#define LC_   64

typedef unsigned short ushortT;
typedef short bf16x8 __attribute__((ext_vector_type(8)));
typedef float f32x4 __attribute__((ext_vector_type(4)));

typedef __attribute__((address_space(3))) uint32_t lds_u32_t;
typedef __attribute__((address_space(1))) const uint32_t glb_u32_t;

static __device__ __forceinline__ void stage16(const void* g, void* lds) {
    __builtin_amdgcn_global_load_lds(
        (glb_u32_t*)(uintptr_t)g,
        (lds_u32_t*)(uint32_t)(uintptr_t)lds,
        16, 0, 0);
}

static __device__ __forceinline__ float silu_f(float x) {
    return x / (1.0f + __expf(-x));
}
// fast softplus: ln(1+e^s) = max(s,0) + ln(1+e^-|s|)   (no libm log1pf)
static __device__ __forceinline__ float softplus_f(float s) {
    return fmaxf(s, 0.0f) + __logf(1.0f + __expf(-fabsf(s)));
}
static __device__ __forceinline__ ushortT f2bf(float f) {
    union { float f; uint32_t u; } v; v.f = f;
    uint32_t u = v.u;
    uint32_t r = u + 0x7fffu + ((u >> 16) & 1u);
    return (ushortT)(r >> 16);
}
static __device__ __forceinline__ float bf2f(ushortT b) {
    union { uint32_t u; float f; } v; v.u = ((uint32_t)b) << 16;
    return v.f;
}

// ---------------------------------------------------------------------------
// Weight conversions: in_proj, out_proj fp32->bf16; xproj fp32->bf16 padded
// to 64 rows (rows 56..63 zero).
// ---------------------------------------------------------------------------
__global__ __launch_bounds__(256) void wconv_kernel(
    const float* __restrict__ w1, int n1, const float* __restrict__ w2, int n2,
    const float* __restrict__ xwf, const float* __restrict__ xwb,
    ushortT* __restrict__ o1, ushortT* __restrict__ o2,
    ushortT* __restrict__ oxf, ushortT* __restrict__ oxb)
{
    int i = blockIdx.x * 256 + threadIdx.x;
    if (i < n1) { o1[i] = f2bf(w1[i]); return; }
    i -= n1;
    if (i < n2) { o2[i] = f2bf(w2[i]); return; }
    i -= n2;
    const int nx = NDBCP * DI_;
    if (i < 2 * nx) {
        int which = i >= nx;
        int j = which ? (i - nx) : i;
        int row = j / DI_;
        const float* src = which ? xwb : xwf;
        ushortT* dst = which ? oxb : oxf;
        dst[j] = (row < NDBC_) ? f2bf(src[j]) : (ushortT)0;
    }
}

// ---------------------------------------------------------------------------
// LayerNorm: one wave per row of 384; block = 4 rows. Writes bf16.
// ---------------------------------------------------------------------------
__global__ __launch_bounds__(256) void ln_kernel(
    const float* __restrict__ x, const float* __restrict__ w,
    const float* __restrict__ b, ushortT* __restrict__ xn,
    int row0, int nrows)
{
    int r = blockIdx.x * 4 + (threadIdx.x >> 6);
    if (r >= nrows) return;
    int lane = threadIdx.x & 63;
    const float* xr = x + (size_t)(row0 + r) * DM_;
    float v[6];
    float s = 0.0f;
#pragma unroll
    for (int i = 0; i < 6; i++) { v[i] = xr[lane + 64 * i]; s += v[i]; }
#pragma unroll
    for (int o = 32; o > 0; o >>= 1) s += __shfl_down(s, o, 64);
    s = __shfl(s, 0, 64);
    float mu = s * (1.0f / DM_);
    float q = 0.0f;
#pragma unroll
    for (int i = 0; i < 6; i++) { float d = v[i] - mu; q += d * d; }
#pragma unroll
    for (int o = 32; o > 0; o >>= 1) q += __shfl_down(q, o, 64);
    q = __shfl(q, 0, 64);
    float rstd = rsqrtf(q * (1.0f / DM_) + 1e-5f);
    ushortT* outp = xn + (size_t)r * DM_;
#pragma unroll
    for (int i = 0; i < 6; i++) {
        int c = lane + 64 * i;
        outp[c] = f2bf((v[i] - mu) * rstd * w[c] + b[c]);
    }
}

// ---------------------------------------------------------------------------
// bf16 MFMA GEMM (m97-style): C[M x N] = [Aa | Ab] * W^T (+ R)
// ---------------------------------------------------------------------------
template <int BM, int BN, int WR, int WC, bool CAT, bool RES>
__global__ __launch_bounds__(256) void gemm_mfma(
    const ushortT* __restrict__ Aa, const ushortT* __restrict__ Ab_,
    const ushortT* __restrict__ W, const float* __restrict__ R,
    float* __restrict__ C, int M, int N, int Khalf)
{
    constexpr int WTM = BM / WR;
    constexpr int WTN = BN / WC;
    constexpr int FM = WTM / 16;
    constexpr int FN = WTN / 16;
    __shared__ ushortT As[BM * 32];
    __shared__ ushortT Ws[BN * 32];
    int tid = threadIdx.x;
    int bm = blockIdx.x * BM, bn = blockIdx.y * BN;
    int wave = tid >> 6, lane = tid & 63;
    int wm = wave % WR, wn = wave / WR;
    f32x4 acc[FM][FN] = {};
    int Ktot = CAT ? 2 * Khalf : Khalf;
    int lrow = lane >> 2;
    int lk = (lane & 3) * 8;

    for (int k0 = 0; k0 < Ktot; k0 += 32) {
        const ushortT* Asrc = (!CAT || k0 < Khalf) ? Aa : Ab_;
        int ka = (!CAT || k0 < Khalf) ? k0 : (k0 - Khalf);
        __syncthreads();
#pragma unroll
        for (int c = 0; c < BM / 64; c++) {
            int ch = c * 4 + wave;
            int row = ch * 16 + lrow;
            stage16(Asrc + (size_t)(bm + row) * Khalf + ka + lk, &As[ch * 16 * 32]);
        }
#pragma unroll
        for (int c = 0; c < BN / 64; c++) {
            int ch = c * 4 + wave;
            int row = ch * 16 + lrow;
            stage16(W + (size_t)(bn + row) * Khalf + ka + lk, &Ws[ch * 16 * 32]);
        }
        __syncthreads();
        int mb = (wm * WTM + (lane & 15)) * 32 + (lane >> 4) * 8;
        int nb = (wn * WTN + (lane & 15)) * 32 + (lane >> 4) * 8;
        bf16x8 af[FM], bfr[FN];
#pragma unroll
        for (int mi = 0; mi < FM; mi++) af[mi] = *(bf16x8*)&As[mb + mi * 16 * 32];
#pragma unroll
        for (int ni = 0; ni < FN; ni++) bfr[ni] = *(bf16x8*)&Ws[nb + ni * 16 * 32];
#pragma unroll
        for (int mi = 0; mi < FM; mi++)
#pragma unroll
            for (int ni = 0; ni < FN; ni++)
                acc[mi][ni] = __builtin_amdgcn_mfma_f32_16x16x32_bf16(
                    af[mi], bfr[ni], acc[mi][ni], 0, 0, 0);
    }

#pragma unroll
    for (int mi = 0; mi < FM; mi++) {
        int row = bm + wm * WTM + 16 * mi + (lane >> 4) * 4;
#pragma unroll
        for (int ni = 0; ni < FN; ni++) {
            int col = bn + wn * WTN + 16 * ni + (lane & 15);
#pragma unroll
            for (int r = 0; r < 4; r++) {
                size_t o = (size_t)(row + r) * N + col;
                float v = acc[mi][ni][r];
                if (RES) v += R[o];
                C[o] = v;
            }
        }
    }
}

// ---------------------------------------------------------------------------
// xproj MFMA: C[dir][M x 64] = XH[dir-half] * Wpad^T. BM=64, BN=64 (padded),
// both dirs in one grid (block row selects dir/W/C). K=768.
// ---------------------------------------------------------------------------
__global__ __launch_bounds__(256) void xproj_mfma(
    const ushortT* __restrict__ XH, const ushortT* __restrict__ Wf,
    const ushortT* __restrict__ Wb, float* __restrict__ Cf,
    float* __restrict__ Cb, int mblocksPerDir)
{
    __shared__ ushortT As[64 * 32];
    __shared__ ushortT Ws[64 * 32];
    int blk = blockIdx.x;
    int dir = blk >= mblocksPerDir;
    const ushortT* W = dir ? Wb : Wf;
    float* C = dir ? Cb : Cf;
    int bmG = blk * 64;
    int bmC = (blk - dir * mblocksPerDir) * 64;
    int tid = threadIdx.x, wave = tid >> 6, lane = tid & 63;
    f32x4 acc[4] = {};
    int lrow = lane >> 2;
    int lk = (lane & 3) * 8;

    for (int k0 = 0; k0 < DI_; k0 += 32) {
        __syncthreads();
        stage16(XH + (size_t)(bmG + wave * 16 + lrow) * DI_ + k0 + lk, &As[wave * 16 * 32]);
        stage16(W + (size_t)(wave * 16 + lrow) * DI_ + k0 + lk, &Ws[wave * 16 * 32]);
        __syncthreads();
        bf16x8 bfr = *(bf16x8*)&Ws[(wave * 16 + (lane & 15)) * 32 + (lane >> 4) * 8];
#pragma unroll
        for (int mi = 0; mi < 4; mi++) {
            bf16x8 af = *(bf16x8*)&As[(mi * 16 + (lane & 15)) * 32 + (lane >> 4) * 8];
            acc[mi] = __builtin_amdgcn_mfma_f32_16x16x32_bf16(af, bfr, acc[mi], 0, 0, 0);
        }
    }
#pragma unroll
    for (int mi = 0; mi < 4; mi++) {
        int row = bmC + 16 * mi + (lane >> 4) * 4;
        int col = wave * 16 + (lane & 15);
#pragma unroll
        for (int r = 0; r < 4; r++)
            C[(size_t)(row + r) * NDBCP + col] = acc[mi][r];
    }
}

// ---------------------------------------------------------------------------
// Causal depthwise conv (K=4) + silu, float4 over d; writes bf16 XH
// (concatenated: dir 0 rows [0,rows), dir 1 rows [rows, 2*rows)).
// ---------------------------------------------------------------------------
__global__ __launch_bounds__(256) void conv_kernel(
    const float* __restrict__ xz,
    const float* __restrict__ wf, const float* __restrict__ bf,
    const float* __restrict__ wb, const float* __restrict__ bb,
    ushortT* __restrict__ xh, int gB)
{
    const int DQ = DI_ / 4;
    int idx = blockIdx.x * 256 + threadIdx.x;
    int perdir = gB * LN_ * DQ;
    int dir = 0;
    if (idx >= perdir) { idx -= perdir; dir = 1; }
    int dq = idx % DQ;
    int l = (idx / DQ) & (LN_ - 1);
    int b = idx / (DQ * LN_);
    int d4 = dq * 4;
    const float4* w4 = (const float4*)(dir ? wb : wf);
    float4 wv0 = w4[d4 + 0], wv1 = w4[d4 + 1], wv2 = w4[d4 + 2], wv3 = w4[d4 + 3];
    const float* wp0 = (const float*)&wv0;
    const float* wp1 = (const float*)&wv1;
    const float* wp2 = (const float*)&wv2;
    const float* wp3 = (const float*)&wv3;
    float4 bias = *(const float4*)((dir ? bb : bf) + d4);
    float s0 = bias.x, s1 = bias.y, s2 = bias.z, s3 = bias.w;
#pragma unroll
    for (int k = 0; k < 4; k++) {
        int j = l - 3 + k;
        if (j < 0) continue;
        int ls = dir ? (LN_ - 1 - j) : j;
        float4 xv = *(const float4*)(xz + ((size_t)(b * LN_ + ls)) * (2 * DI_) + d4);
        s0 = fmaf(xv.x, wp0[k], s0);
        s1 = fmaf(xv.y, wp1[k], s1);
        s2 = fmaf(xv.z, wp2[k], s2);
        s3 = fmaf(xv.w, wp3[k], s3);
    }
    ushortT* op = xh + ((size_t)dir * gB * LN_ + (size_t)(b * LN_ + l)) * DI_ + d4;
    ushort4 o;
    o.x = f2bf(silu_f(s0)); o.y = f2bf(silu_f(s1));
    o.z = f2bf(silu_f(s2)); o.w = f2bf(silu_f(s3));
    *(ushort4*)op = o;
}

// ---------------------------------------------------------------------------
// Chunked selective scan (3 phases), dt-projection fused.
// ILP-tuned: split dot, power tree, split yv accumulators, int indices,
// fast softplus. A=-(n+1)*a1 fast path guarded at runtime.
// ---------------------------------------------------------------------------
__global__ __launch_bounds__(256) void scan1_kernel(
    const ushortT* __restrict__ XH, const float* __restrict__ dbcf,
    const float* __restrict__ dbcb,
    const float* __restrict__ dtwf, const float* __restrict__ dtbf,
    const float* __restrict__ alogf,
    const float* __restrict__ dtwb, const float* __restrict__ dtbb,
    const float* __restrict__ alogb,
    float* __restrict__ hs1, float* __restrict__ dec, int gB)
{
    int bid = blockIdx.x;
    int c = bid % NC_; bid /= NC_;
    int dchunk = bid % 3; bid /= 3;
    int b = bid % gB;
    int dir = bid / gB;
    int d = dchunk * 256 + threadIdx.x;

    const ushortT* xh = XH + (size_t)dir * gB * LN_ * DI_;
    const float* dbc  = dir ? dbcb : dbcf;
    const float* dtw  = (dir ? dtwb : dtwf) + d * RDT_;
    float dtb         = (dir ? dtbb : dtbf)[d];
    const float* alog = dir ? alogb : alogf;

    float An[NS_];
#pragma unroll
    for (int n = 0; n < NS_; n++) An[n] = -__expf(alog[d * NS_ + n]);
    float a1 = An[0];
    bool pk = true;
#pragma unroll
    for (int n = 0; n < NS_; n++)
        pk = pk && (fabsf(An[n] - (float)(n + 1) * a1) <=
                    1e-3f * (float)(n + 1) * fabsf(a1) + 1e-6f);
    pk = (bool)__all((int)pk);

    float wrow[RDT_];
#pragma unroll
    for (int r = 0; r < RDT_; r++) wrow[r] = dtw[r];

    __shared__ float sdbc[LC_ * NDBCP];
    int rb = b * LN_ + c * LC_;
#pragma unroll
    for (int i = 0; i < 4; i++) {
        int idx = threadIdx.x + 256 * i;   // 0..1023 = 64 rows x 16 granules
        int row = idx >> 4, c4 = (idx & 15) * 4;
        *(float4*)&sdbc[row * NDBCP + c4] =
            *(const float4*)(dbc + (size_t)(rb + row) * NDBCP + c4);
    }
    __syncthreads();

    float h[NS_];
#pragma unroll
    for (int n = 0; n < NS_; n++) h[n] = 0.0f;
    float S = 0.0f;

    if (pk) {
        for (int lr = 0; lr < LC_; lr++) {
            const float* rowp = &sdbc[lr * NDBCP];
            float s0 = dtb, s1 = 0.f, s2 = 0.f, s3 = 0.f;
#pragma unroll
            for (int r = 0; r < 6; r++) {
                s0 = fmaf(rowp[r], wrow[r], s0);
                s1 = fmaf(rowp[6 + r], wrow[6 + r], s1);
                s2 = fmaf(rowp[12 + r], wrow[12 + r], s2);
                s3 = fmaf(rowp[18 + r], wrow[18 + r], s3);
            }
            float dt = softplus_f((s0 + s1) + (s2 + s3));
            S += dt;
            float u = bf2f(xh[(rb + lr) * DI_ + d]);
            float du = dt * u;
            float q1 = __expf(dt * a1);
            float q2 = q1 * q1, q4 = q2 * q2, q8 = q4 * q4;
            float p2 = q2, p3 = q2 * q1, p5 = q4 * q1, p6 = q4 * q2, p7 = q4 * p3;
            float pw[NS_] = {q1, p2, p3, q4, p5, p6, p7, q8,
                             q8 * q1, q8 * p2, q8 * p3, q8 * q4,
                             q8 * p5, q8 * p6, q8 * p7, q8 * q8};
#pragma unroll
            for (int n = 0; n < NS_; n++)
                h[n] = fmaf(h[n], pw[n], du * rowp[RDT_ + n]);
        }
        float q1 = __expf(S * a1);
        float q2 = q1 * q1, q4 = q2 * q2, q8 = q4 * q4;
        float p2 = q2, p3 = q2 * q1, p5 = q4 * q1, p6 = q4 * q2, p7 = q4 * p3;
        float pw[NS_] = {q1, p2, p3, q4, p5, p6, p7, q8,
                         q8 * q1, q8 * p2, q8 * p3, q8 * q4,
                         q8 * p5, q8 * p6, q8 * p7, q8 * q8};
        int si = (((dir * gB + b) * NC_ + c) * DI_ + d) * NS_;
#pragma unroll
        for (int n = 0; n < NS_; n++) {
            hs1[si + n] = h[n];
            dec[si + n] = pw[n];
        }
    } else {
        for (int lr = 0; lr < LC_; lr++) {
            const float* rowp = &sdbc[lr * NDBCP];
            float s0 = dtb, s1 = 0.f, s2 = 0.f, s3 = 0.f;
#pragma unroll
            for (int r = 0; r < 6; r++) {
                s0 = fmaf(rowp[r], wrow[r], s0);
                s1 = fmaf(rowp[6 + r], wrow[6 + r], s1);
                s2 = fmaf(rowp[12 + r], wrow[12 + r], s2);
                s3 = fmaf(rowp[18 + r], wrow[18 + r], s3);
            }
            float dt = softplus_f((s0 + s1) + (s2 + s3));
            S += dt;
            float u = bf2f(xh[(rb + lr) * DI_ + d]);
            float du = dt * u;
#pragma unroll
            for (int n = 0; n < NS_; n++)
                h[n] = fmaf(h[n], __expf(dt * An[n]), du * rowp[RDT_ + n]);
        }
        int si = (((dir * gB + b) * NC_ + c) * DI_ + d) * NS_;
#pragma unroll
        for (int n = 0; n < NS_; n++) {
            hs1[si + n] = h[n];
            dec[si + n] = __expf(An[n] * S);
        }
    }
}

__global__ __launch_bounds__(256) void scan2_kernel(
    const float* __restrict__ hs1, const float* __restrict__ dec,
    float* __restrict__ hin, int gB)
{
    int e = blockIdx.x * 256 + threadIdx.x;
    int n = e & 15; int e2 = e >> 4;
    int d = e2 % DI_; e2 /= DI_;
    int b = e2 % gB; int dir = e2 / gB;
    int base = (((dir * gB + b) * NC_) * DI_ + d) * NS_ + n;
    float h = 0.0f;
    const int cs = DI_ * NS_;
    for (int c = 0; c < NC_; c++) {
        int idx = base + c * cs;
        hin[idx] = h;
        h = fmaf(h, dec[idx], hs1[idx]);
    }
}

__global__ __launch_bounds__(256) void scan3_kernel(
    const ushortT* __restrict__ XH, const float* __restrict__ dbcf,
    const float* __restrict__ dbcb,
    const float* __restrict__ dtwf, const float* __restrict__ dtbf,
    const float* __restrict__ alogf, const float* __restrict__ dvf,
    const float* __restrict__ dtwb, const float* __restrict__ dtbb,
    const float* __restrict__ alogb, const float* __restrict__ dvb,
    const float* __restrict__ hin, const float* __restrict__ xz,
    ushortT* __restrict__ yf, ushortT* __restrict__ yb, int gB)
{
    int bid = blockIdx.x;
    int c = bid % NC_; bid /= NC_;
    int dchunk = bid % 3; bid /= 3;
    int b = bid % gB;
    int dir = bid / gB;
    int d = dchunk * 256 + threadIdx.x;

    const ushortT* xh = XH + (size_t)dir * gB * LN_ * DI_;
    const float* dbc  = dir ? dbcb : dbcf;
    const float* dtw  = (dir ? dtwb : dtwf) + d * RDT_;
    float dtb         = (dir ? dtbb : dtbf)[d];
    const float* alog = dir ? alogb : alogf;
    float Dd          = (dir ? dvb : dvf)[d];
    ushortT* y        = dir ? yb : yf;

    float An[NS_];
#pragma unroll
    for (int n = 0; n < NS_; n++) An[n] = -__expf(alog[d * NS_ + n]);
    float a1 = An[0];
    bool pk = true;
#pragma unroll
    for (int n = 0; n < NS_; n++)
        pk = pk && (fabsf(An[n] - (float)(n + 1) * a1) <=
                    1e-3f * (float)(n + 1) * fabsf(a1) + 1e-6f);
    pk = (bool)__all((int)pk);

    float wrow[RDT_];
#pragma unroll
    for (int r = 0; r < RDT_; r++) wrow[r] = dtw[r];

    __shared__ float sdbc[LC_ * NDBCP];
    int rb = b * LN_ + c * LC_;
#pragma unroll
    for (int i = 0; i < 4; i++) {
        int idx = threadIdx.x + 256 * i;
        int row = idx >> 4, c4 = (idx & 15) * 4;
        *(float4*)&sdbc[row * NDBCP + c4] =
            *(const float4*)(dbc + (size_t)(rb + row) * NDBCP + c4);
    }
    __syncthreads();

    int si = (((dir * gB + b) * NC_ + c) * DI_ + d) * NS_;
    float h[NS_];
#pragma unroll
    for (int n = 0; n < NS_; n++) h[n] = hin[si + n];

    if (pk) {
        for (int lr = 0; lr < LC_; lr++) {
            const float* rowp = &sdbc[lr * NDBCP];
            float s0 = dtb, s1 = 0.f, s2 = 0.f, s3 = 0.f;
#pragma unroll
            for (int r = 0; r < 6; r++) {
                s0 = fmaf(rowp[r], wrow[r], s0);
                s1 = fmaf(rowp[6 + r], wrow[6 + r], s1);
                s2 = fmaf(rowp[12 + r], wrow[12 + r], s2);
                s3 = fmaf(rowp[18 + r], wrow[18 + r], s3);
            }
            float dt = softplus_f((s0 + s1) + (s2 + s3));
            float u = bf2f(xh[(rb + lr) * DI_ + d]);
            float du = dt * u;
            float q1 = __expf(dt * a1);
            float q2 = q1 * q1, q4 = q2 * q2, q8 = q4 * q4;
            float p2 = q2, p3 = q2 * q1, p5 = q4 * q1, p6 = q4 * q2, p7 = q4 * p3;
            float pw[NS_] = {q1, p2, p3, q4, p5, p6, p7, q8,
                             q8 * q1, q8 * p2, q8 * p3, q8 * q4,
                             q8 * p5, q8 * p6, q8 * p7, q8 * q8};
            float y0 = 0.f, y1 = 0.f, y2 = 0.f, y3 = 0.f;
#pragma unroll
            for (int n = 0; n < NS_; n += 4) {
                h[n + 0] = fmaf(h[n + 0], pw[n + 0], du * rowp[RDT_ + n + 0]);
                h[n + 1] = fmaf(h[n + 1], pw[n + 1], du * rowp[RDT_ + n + 1]);
                h[n + 2] = fmaf(h[n + 2], pw[n + 2], du * rowp[RDT_ + n + 2]);
                h[n + 3] = fmaf(h[n + 3], pw[n + 3], du * rowp[RDT_ + n + 3]);
                y0 = fmaf(h[n + 0], rowp[RDT_ + NS_ + n + 0], y0);
                y1 = fmaf(h[n + 1], rowp[RDT_ + NS_ + n + 1], y1);
                y2 = fmaf(h[n + 2], rowp[RDT_ + NS_ + n + 2], y2);
                y3 = fmaf(h[n + 3], rowp[RDT_ + NS_ + n + 3], y3);
            }
            float yv = ((y0 + y1) + (y2 + y3)) + u * Dd;
            int l = c * LC_ + lr;
            int lo = dir ? (LN_ - 1 - l) : l;
            float z = xz[(size_t)(b * LN_ + lo) * (2 * DI_) + DI_ + d];
            y[(b * LN_ + lo) * DI_ + d] = f2bf(yv * silu_f(z));
        }
    } else {
        for (int lr = 0; lr < LC_; lr++) {
            const float* rowp = &sdbc[lr * NDBCP];
            float s0 = dtb, s1 = 0.f, s2 = 0.f, s3 = 0.f;
#pragma unroll
            for (int r = 0; r < 6; r++) {
                s0 = fmaf(rowp[r], wrow[r], s0);
                s1 = fmaf(rowp[6 + r], wrow[6 + r], s1);
                s2 = fmaf(rowp[12 + r], wrow[12 + r], s2);
                s3 = fmaf(rowp[18 + r], wrow[18 + r], s3);
            }
            float dt = softplus_f((s0 + s1) + (s2 + s3));
            float u = bf2f(xh[(rb + lr) * DI_ + d]);
            float du = dt * u;
            float y0 = 0.f, y1 = 0.f, y2 = 0.f, y3 = 0.f;
#pragma unroll
            for (int n = 0; n < NS_; n += 4) {
                h[n + 0] = fmaf(h[n + 0], __expf(dt * An[n + 0]), du * rowp[RDT_ + n + 0]);
                h[n + 1] = fmaf(h[n + 1], __expf(dt * An[n + 1]), du * rowp[RDT_ + n + 1]);
                h[n + 2] = fmaf(h[n + 2], __expf(dt * An[n + 2]), du * rowp[RDT_ + n + 2]);
                h[n + 3] = fmaf(h[n + 3], __expf(dt * An[n + 3]), du * rowp[RDT_ + n + 3]);
                y0 = fmaf(h[n + 0], rowp[RDT_ + NS_ + n + 0], y0);
                y1 = fmaf(h[n + 1], rowp[RDT_ + NS_ + n + 1], y1);
                y2 = fmaf(h[n + 2], rowp[RDT_ + NS_ + n + 2], y2);
                y3 = fmaf(h[n + 3], rowp[RDT_ + NS_ + n + 3], y3);
            }
            float yv = ((y0 + y1) + (y2 + y3)) + u * Dd;
            int l = c * LC_ + lr;
            int lo = dir ? (LN_ - 1 - l) : l;
            float z = xz[(size_t)(b * LN_ + lo) * (2 * DI_) + DI_ + d];
            y[(b * LN_ + lo) * DI_ + d] = f2bf(yv * silu_f(z));
        }
    }
}

// ---------------------------------------------------------------------------
// Host launcher.
// ---------------------------------------------------------------------------
extern "C" void kernel_launch(void* const* d_in, const int* in_sizes, int n_in,
                              void* d_out, int out_size, void* d_ws, size_t ws_size,
                              hipStream_t stream)
{
    const float* x         = (const float*)d_in[0];
    const float* ln_w      = (const float*)d_in[1];
    const float* ln_b      = (const float*)d_in[2];
    const float* in_proj_w = (const float*)d_in[3];
    const float* out_proj_w= (const float*)d_in[4];
    const float* conv_wf   = (const float*)d_in[5];
    const float* conv_bf   = (const float*)d_in[6];
    const float* xproj_f   = (const float*)d_in[7];
    const float* dt_wf     = (const float*)d_in[8];
    const float* dt_bf     = (const float*)d_in[9];
    const float* alog_f    = (const float*)d_in[10];
    const float* dv_f      = (const float*)d_in[11];
    const float* conv_wb   = (const float*)d_in[12];
    const float* conv_bb   = (const float*)d_in[13];
    const float* xproj_b   = (const float*)d_in[14];
    const float* dt_wb     = (const float*)d_in[15];
    const float* dt_bb     = (const float*)d_in[16];
    const float* alog_b    = (const float*)d_in[17];
    const float* dv_b      = (const float*)d_in[18];
    float* outp = (float*)d_out;

    const int n_w1 = 2 * DI_ * DM_;
    const int n_w2 = DM_ * DI_;
    const int n_wx = NDBCP * DI_;

    uint8_t* base = (uint8_t*)d_ws;
    size_t off = 0;
    auto alloc = [&](size_t nbytes) {
        uint8_t* r = base + off;
        off = (off + nbytes + 255) & ~(size_t)255;
        return r;
    };
    ushortT* WbIn  = (ushortT*)alloc((size_t)n_w1 * 2);
    ushortT* WbOut = (ushortT*)alloc((size_t)n_w2 * 2);
    ushortT* WbXf  = (ushortT*)alloc((size_t)n_wx * 2);
    ushortT* WbXb  = (ushortT*)alloc((size_t)n_wx * 2);
    size_t fixed_bytes = off;

    size_t per_b_bytes = 20ull * 1024 * 1024;
    int g = BN_;
    while (g > 1 && fixed_bytes + (size_t)g * per_b_bytes + (1ull << 20) > ws_size) g >>= 1;

    wconv_kernel<<<(n_w1 + n_w2 + 2 * n_wx + 255) / 256, 256, 0, stream>>>(
        in_proj_w, n_w1, out_proj_w, n_w2, xproj_f, xproj_b,
        WbIn, WbOut, WbXf, WbXb);

    for (int b0 = 0; b0 < BN_; b0 += g) {
        int rows = g * LN_;
        off = fixed_bytes;
        ushortT* XNb = (ushortT*)alloc((size_t)rows * DM_ * 2);
        float* XZ    = (float*)alloc((size_t)rows * 2 * DI_ * 4);
        ushortT* XH  = (ushortT*)alloc((size_t)2 * rows * DI_ * 2);
        float* DBCf  = (float*)alloc((size_t)rows * NDBCP * 4);
        float* DBCb  = (float*)alloc((size_t)rows * NDBCP * 4);
        size_t st_n  = (size_t)2 * g * NC_ * DI_ * NS_;
        float* HS1   = (float*)alloc(st_n * 4);
        float* DEC   = (float*)alloc(st_n * 4);
        float* HIN   = (float*)alloc(st_n * 4);
        ushortT* Yf  = (ushortT*)alloc((size_t)rows * DI_ * 2);
        ushortT* Yb  = (ushortT*)alloc((size_t)rows * DI_ * 2);
        int row0 = b0 * LN_;

        ln_kernel<<<rows / 4, 256, 0, stream>>>(x, ln_w, ln_b, XNb, row0, rows);

        gemm_mfma<128, 128, 2, 2, false, false>
            <<<dim3(rows / 128, (2 * DI_) / 128), 256, 0, stream>>>(
            XNb, nullptr, WbIn, nullptr, XZ, rows, 2 * DI_, DM_);

        conv_kernel<<<(2 * rows * (DI_ / 4)) / 256, 256, 0, stream>>>(
            XZ, conv_wf, conv_bf, conv_wb, conv_bb, XH, g);

        xproj_mfma<<<2 * (rows / 64), 256, 0, stream>>>(
            XH, WbXf, WbXb, DBCf, DBCb, rows / 64);

        scan1_kernel<<<2 * g * 3 * NC_, 256, 0, stream>>>(
            XH, DBCf, DBCb, dt_wf, dt_bf, alog_f,
            dt_wb, dt_bb, alog_b, HS1, DEC, g);

        scan2_kernel<<<(2 * g * DI_ * NS_) / 256, 256, 0, stream>>>(HS1, DEC, HIN, g);

        scan3_kernel<<<2 * g * 3 * NC_, 256, 0, stream>>>(
            XH, DBCf, DBCb, dt_wf, dt_bf, alog_f, dv_f,
            dt_wb, dt_bb, alog_b, dv_b, HIN, XZ, Yf, Yb, g);

        gemm_mfma<64, 128, 1, 4, true, true>
            <<<dim3(rows / 64, DM_ / 128), 256, 0, stream>>>(
            Yf, Yb, WbOut, x + (size_t)row0 * DM_,
            outp + (size_t)row0 * DM_, rows, DM_, DI_);
    }
}